// Round 10
// baseline (124.064 us; speedup 1.0000x reference)
//
#include <hip/hip_runtime.h>
#include <math.h>

#define BB 512
#define DD 16
#define NN 64
#define MM 32
#define RR 32
#define CC 10
#define BBLK 8           // b's per chain block = waves per block (1 chain/wave)
#define ROWH 40          // halves per LDS row (80 B, 16B-aligned)
#define BREGH 1304       // halves per b region (bank-spread stride)

typedef _Float16 v8h __attribute__((ext_vector_type(8)));
typedef float v4f __attribute__((ext_vector_type(4)));

union H8 { unsigned int u[4]; v8h h; _Float16 e[8]; };
union H4 { unsigned int u[2]; _Float16 e[4]; };

// ---------------------------------------------------------------------------
// Kernel 1 (merged producers, fully coalesced via LDS staging — r9 version):
//  blocks [0,1024):    feat_h = fp16( tensor @ W + b )   [B][D][M]
//  blocks [1024,1344): per (c,d,half-slab): G -> gh in MFMA B-frag order
//    gh[(((c*16+d)*64 + tile)*64 + lane)*8 + r] =
//        fp16( G[c][d][i=tile>>1][m=8*(lane>>4)+r][j=16*(tile&1)+(lane&15)] )
// ---------------------------------------------------------------------------
__global__ __launch_bounds__(256) void produce_kernel(
    const float* __restrict__ tensor, const float* __restrict__ W,
    const float* __restrict__ bias,   const float* __restrict__ G,
    _Float16* __restrict__ fh,        _Float16* __restrict__ gh) {
    __shared__ __align__(16) char smem[36864];
    const int t = threadIdx.x;
    if (blockIdx.x < 1024) {
        float* ten_s = (float*)smem;          // [8][64]
        float* W_s   = (float*)smem + 512;    // [64][32]
        const int bd0 = blockIdx.x * 8;
        if (t < 128)
            *(float4*)(ten_s + t * 4) = *(const float4*)(tensor + bd0 * NN + t * 4);
        *(float4*)(W_s + t * 4)        = *(const float4*)(W + t * 4);
        *(float4*)(W_s + 1024 + t * 4) = *(const float4*)(W + 1024 + t * 4);
        __syncthreads();
        const int m = t & 31, bd_l = t >> 5;
        float acc = bias[m];
#pragma unroll
        for (int n = 0; n < NN; ++n) acc += ten_s[bd_l * NN + n] * W_s[n * MM + m];
        fh[(bd0 + bd_l) * MM + m] = (_Float16)acc;
    } else {
        _Float16* lg = (_Float16*)smem;       // [di][m][j], m-stride 36 halves
        const int pb = blockIdx.x - 1024;     // 0..319
        const int c  = pb >> 5;
        const int d  = (pb >> 1) & 15;
        const int hf = pb & 1;
        const float* src = G + (size_t)(c * DD + d) * 32768 + hf * 16384;
#pragma unroll
        for (int k = 0; k < 16; ++k) {        // coalesced read of 64 KB slab-half
            const int f = (k * 256 + t) * 4;
            float4 v = *(const float4*)(src + f);
            const int di = f >> 10, m = (f >> 5) & 31, j = f & 31;
            H4 hv;
            hv.e[0] = (_Float16)v.x; hv.e[1] = (_Float16)v.y;
            hv.e[2] = (_Float16)v.z; hv.e[3] = (_Float16)v.w;
            *(uint2*)(lg + di * 1152 + m * 36 + j) = make_uint2(hv.u[0], hv.u[1]);
        }
        __syncthreads();
#pragma unroll
        for (int k = 0; k < 8; ++k) {         // coalesced 16B fragment writes
            const int idx = k * 256 + t;
            const int tl = idx >> 6, ln = idx & 63;
            const int di = tl >> 1;
            const int q = ln >> 4, j4 = ln & 15;
            const int j = (tl & 1) * 16 + j4;
            H8 o;
#pragma unroll
            for (int r = 0; r < 8; ++r)
                o.e[r] = lg[di * 1152 + (8 * q + r) * 36 + j];
            const size_t gi = ((size_t)(c * DD + d) * 64 + hf * 32 + tl) * 64 + ln;
            *(v8h*)(gh + gi * 8) = o.h;
        }
    }
}

// ---------------------------------------------------------------------------
// Kernel 2: per (c, b-block of 8): full 16-d chain in one block, trace from
// registers — no segment products, no combine kernel (r8 structure) + r9's
// XCD swizzle: c = bid&7 pins each class's 80-block working set (~2.1 MB of
// gh) to one XCD's L2 (r8 lesson: 640 MB of L3-side G re-reads at 850 GB/s
// was the chain ceiling). G fragments register-prefetched one d ahead.
// ---------------------------------------------------------------------------
__global__ __launch_bounds__(512, 4) void chain_kernel(
    const _Float16* __restrict__ feat_h,
    const _Float16* __restrict__ g_h,
    float* __restrict__ logits)        // [B][C]
{
    __shared__ __align__(16) _Float16 lds[BBLK * BREGH];  // 20864 B

    const int bid = blockIdx.x;        // 0..639
    const int xcd = bid & 7;
    const int idx = bid >> 3;          // 0..79
    int c, sub;
    if (idx < 64) { c = xcd; sub = idx; }
    else {
        const int e = idx - 64;        // 0..15
        if (xcd < 4) { c = 8; sub = xcd * 16 + e; }
        else         { c = 9; sub = (xcd - 4) * 16 + e; }
    }
    const int b0 = sub * BBLK;

    const int t    = threadIdx.x;
    const int w    = t >> 6;           // wave 0..7, chains b = b0 + w
    const int lane = t & 63;
    const int q    = lane >> 4;        // 0..3
    const int j4   = lane & 15;

    const size_t gbase_c = (size_t)c * DD * 32768;
    const int bA = b0 + (j4 & 7);      // A rows: j4 0..7 valid, 8..15 duplicates

    // ---- prefetch d = 0 fragments into registers ----
    v8h afh = *(const v8h*)(feat_h + (size_t)bA * (DD * MM) + q * 8);
    v8h gf[8];
#pragma unroll
    for (int u = 0; u < 8; ++u)        // u = 2*ii + jh; core row k = 4w + ii
        gf[u] = *(const v8h*)(g_h + gbase_c + ((size_t)(w * 8 + u) * 64 + lane) * 8);

    v8h pah[2];
    v4f acc[2][2];

    for (int d = 0; d < DD; ++d) {
        __syncthreads();   // WAR: previous p2 reads of lds done
        // ---------------- phase 1: 8 MFMAs on prefetched fragments -------
        v4f av[8];
#pragma unroll
        for (int u = 0; u < 8; ++u) {
            v4f z = {0.f, 0.f, 0.f, 0.f};
            av[u] = __builtin_amdgcn_mfma_f32_16x16x32_f16(afh, gf[u], z, 0, 0, 0);
        }
        // ---- issue d+1 prefetch now: overlaps stores, p2, both barriers --
        if (d < DD - 1) {
            afh = *(const v8h*)(feat_h + (size_t)bA * (DD * MM) + (d + 1) * MM + q * 8);
            const size_t gb = gbase_c + (size_t)(d + 1) * 32768;
#pragma unroll
            for (int u = 0; u < 8; ++u)
                gf[u] = *(const v8h*)(g_h + gb + ((size_t)(w * 8 + u) * 64 + lane) * 8);
        }
        // store core rows for valid b's (row = 4q+reg < 8  ->  q < 2)
        if (q < 2) {
#pragma unroll
            for (int jh = 0; jh < 2; ++jh)
#pragma unroll
                for (int reg = 0; reg < 4; ++reg) {
                    H4 hv;
                    hv.e[0] = (_Float16)av[0 + jh][reg];   // k = 4w+0
                    hv.e[1] = (_Float16)av[2 + jh][reg];   // k = 4w+1
                    hv.e[2] = (_Float16)av[4 + jh][reg];
                    hv.e[3] = (_Float16)av[6 + jh][reg];
                    *reinterpret_cast<uint2*>(
                        &lds[(4 * q + reg) * BREGH + (16 * jh + j4) * ROWH + 4 * w]) =
                        make_uint2(hv.u[0], hv.u[1]);
                }
        }
        __syncthreads();   // RAW: cores ready
        // ---------------- phase 2: wave w advances its chain -------------
        _Float16* base = lds + w * BREGH;
        if (d == 0) {
            // P = core_0: A[m=16mi+j4][k=8q+r] = core[m][k] = L[k][m]
#pragma unroll
            for (int mi = 0; mi < 2; ++mi) {
                H8 a;
#pragma unroll
                for (int r = 0; r < 8; ++r)
                    a.e[r] = base[(8 * q + r) * ROWH + 16 * mi + j4];
                pah[mi] = a.h;
            }
        } else {
            v8h bf[2];
#pragma unroll
            for (int ni = 0; ni < 2; ++ni)
                bf[ni] = *(const v8h*)(base + (16 * ni + j4) * ROWH + 8 * q);
#pragma unroll
            for (int mi = 0; mi < 2; ++mi)
#pragma unroll
                for (int ni = 0; ni < 2; ++ni) {
                    v4f z = {0.f, 0.f, 0.f, 0.f};
                    acc[mi][ni] = __builtin_amdgcn_mfma_f32_16x16x32_f16(
                        pah[mi], bf[ni], z, 0, 0, 0);
                }
            if (d < DD - 1) {
                // round-trip: store P_new [row][col] fp16, read back A-frags
#pragma unroll
                for (int mi = 0; mi < 2; ++mi)
#pragma unroll
                    for (int ni = 0; ni < 2; ++ni)
#pragma unroll
                        for (int reg = 0; reg < 4; ++reg)
                            base[(16 * mi + 4 * q + reg) * ROWH + 16 * ni + j4] =
                                (_Float16)acc[mi][ni][reg];
                __builtin_amdgcn_sched_barrier(0);  // reads after writes
#pragma unroll
                for (int mi = 0; mi < 2; ++mi)
                    pah[mi] = *(const v8h*)(base + (16 * mi + j4) * ROWH + 8 * q);
            }
        }
    }

    // trace from final accumulators: row = 16mi+4q+reg, col = 16ni+j4;
    // diagonal (mi==ni) hit iff 4q+reg == j4
    float tr = 0.f;
    if (q == (j4 >> 2)) {
        int reg = j4 & 3;
        tr = acc[0][0][reg] + acc[1][1][reg];
    }
#pragma unroll
    for (int off = 32; off > 0; off >>= 1) tr += __shfl_down(tr, off);
    if (lane == 0) logits[(b0 + w) * CC + c] = tr;
}

// ---------------------------------------------------------------------------
// Kernel 3: log-softmax over c, one thread per b
// ---------------------------------------------------------------------------
__global__ void lsm_kernel(const float* __restrict__ logits,
                           float* __restrict__ out) {
    int b = blockIdx.x * blockDim.x + threadIdx.x;
    if (b >= BB) return;
    float x[CC];
    float mx = -1e30f;
#pragma unroll
    for (int c = 0; c < CC; ++c) { x[c] = logits[b * CC + c]; mx = fmaxf(mx, x[c]); }
    float s = 0.f;
#pragma unroll
    for (int c = 0; c < CC; ++c) s += expf(x[c] - mx);
    float ls = logf(s);
#pragma unroll
    for (int c = 0; c < CC; ++c) out[b * CC + c] = x[c] - mx - ls;
}

// ---------------------------------------------------------------------------
extern "C" void kernel_launch(void* const* d_in, const int* in_sizes, int n_in,
                              void* d_out, int out_size, void* d_ws, size_t ws_size,
                              hipStream_t stream) {
    const float* tensor = (const float*)d_in[0];
    const float* W      = (const float*)d_in[1];
    const float* bias   = (const float*)d_in[2];
    const float* G      = (const float*)d_in[3];
    float* out = (float*)d_out;

    const size_t FEAT = (size_t)BB * DD * MM;          // 262144 halves
    const size_t GPK  = (size_t)CC * DD * 64 * 64 * 8; // 5242880 halves
    _Float16* fh = (_Float16*)d_ws;
    _Float16* gh = fh + FEAT;
    float* logits = (float*)(gh + GPK);                // 5120 floats; ws ~11 MB

    produce_kernel<<<1024 + 320, 256, 0, stream>>>(tensor, W, bias, G, fh, gh);
    chain_kernel<<<CC * (BB / BBLK), 512, 0, stream>>>(fh, gh, logits);
    lsm_kernel<<<(BB + 255) / 256, 256, 0, stream>>>(logits, out);
}